// Round 11
// baseline (592.472 us; speedup 1.0000x reference)
//
#include <hip/hip_runtime.h>

#define N_NODES 100000
#define DIM     128
#define RR      100
#define NE      400000
#define NBLK    196    // ceil(N_NODES / 512)
#define NPB     32     // dst nodes per fused block (100000 = 3125 * 32, exact)

typedef float  floatx4 __attribute__((ext_vector_type(4)));
typedef float  floatx2 __attribute__((ext_vector_type(2)));
typedef __bf16 bf16x8  __attribute__((ext_vector_type(8)));

static __device__ __forceinline__ unsigned short f2b(float f) {
    union { float f; unsigned int i; } v; v.f = f;
    unsigned int u = v.i;
    unsigned int r = (u + 0x7fffu + ((u >> 16) & 1u)) >> 16;   // RNE
    return (unsigned short)r;
}
static __device__ __forceinline__ float b2f(unsigned int u16) {
    union { unsigned int i; float f; } v; v.i = u16 << 16; return v.f;
}
static __device__ __forceinline__ unsigned packbf(float a, float b) {
    return (unsigned)f2b(a) | ((unsigned)f2b(b) << 16);
}

// ---- per-dst degree ------------------------------------------------------
__global__ void k_deg(const int* __restrict__ dst, int* __restrict__ deg, int E) {
    int e = blockIdx.x * 256 + threadIdx.x;
    if (e < E) atomicAdd(&deg[dst[e]], 1);
}

// ---- 2-level exclusive scan over deg[N] ----------------------------------
__global__ void k_scan_block(const int* __restrict__ deg, int* __restrict__ bsum) {
    __shared__ int sm[256];
    int b = blockIdx.x, t = threadIdx.x;
    int i0 = b * 512 + 2 * t;
    int a = (i0     < N_NODES) ? deg[i0]     : 0;
    int c = (i0 + 1 < N_NODES) ? deg[i0 + 1] : 0;
    sm[t] = a + c;
    __syncthreads();
    for (int s = 128; s > 0; s >>= 1) { if (t < s) sm[t] += sm[t + s]; __syncthreads(); }
    if (t == 0) bsum[b] = sm[0];
}

__global__ void k_scan_top(const int* __restrict__ bsum, int* __restrict__ boff) {
    __shared__ int sm[256];
    int t = threadIdx.x;
    int v = (t < NBLK) ? bsum[t] : 0;
    sm[t] = v;
    __syncthreads();
    for (int s = 1; s < 256; s <<= 1) {
        int u = (t >= s) ? sm[t - s] : 0;
        __syncthreads();
        sm[t] += u;
        __syncthreads();
    }
    if (t < NBLK) boff[t] = sm[t] - v;   // exclusive
}

__global__ void k_scan_down(const int* __restrict__ deg, const int* __restrict__ boff,
                            int* __restrict__ off) {
    __shared__ int sm[256];
    int b = blockIdx.x, t = threadIdx.x;
    int i0 = b * 512 + 2 * t;
    int a = (i0     < N_NODES) ? deg[i0]     : 0;
    int c = (i0 + 1 < N_NODES) ? deg[i0 + 1] : 0;
    int ts = a + c;
    sm[t] = ts;
    __syncthreads();
    for (int s = 1; s < 256; s <<= 1) {
        int u = (t >= s) ? sm[t - s] : 0;
        __syncthreads();
        sm[t] += u;
        __syncthreads();
    }
    int base = boff[b] + (sm[t] - ts);
    if (i0     < N_NODES) off[i0]     = base;
    if (i0 + 1 < N_NODES) off[i0 + 1] = base + a;
    if (b == 0 && t == 0) off[N_NODES] = NE;
}

// ---- scatter edges into dst-sorted CSR: desc = {src, et<<19|eidx, dst, norm}
__global__ void k_scatter(const int* __restrict__ src, const int* __restrict__ dst,
                          const int* __restrict__ et, const int* __restrict__ off,
                          int* __restrict__ cursor, int4* __restrict__ edesc, int E) {
    int e = blockIdx.x * 256 + threadIdx.x;
    if (e >= E) return;
    int d = dst[e];
    int pos = off[d] + atomicAdd(&cursor[d], 1);
    edesc[pos] = make_int4(src[e], (et[e] << 19) | e, d, 0);
}

// ---- schlichtkrull norm: one thread per CSR slot, O(deg) scan ------------
__global__ void k_norm2(const int* __restrict__ off, int4* __restrict__ edesc, int E) {
    int p = blockIdx.x * 256 + threadIdx.x;
    if (p >= E) return;
    int4 me = edesc[p];
    int myt = me.y >> 19;
    int p0 = off[me.z], p1 = off[me.z + 1];
    int c = 0;
    for (int j = p0; j < p1; ++j)
        c += ((((const int*)edesc)[4 * j + 1] >> 19) == myt) ? 1 : 0;
    ((int*)edesc)[4 * p + 3] = __float_as_int(1.0f / (float)c);
}

// ---- fused preprocessing: x0 | wt transpose | rel bf16 | penalty | zero --
__global__ void k_pre(const float* __restrict__ ent, const float* __restrict__ entb,
                      const float* __restrict__ bases1, const float* __restrict__ root1,
                      const float* __restrict__ bases2, const float* __restrict__ root2,
                      const float* __restrict__ rel,
                      unsigned short* __restrict__ x1,
                      unsigned short* __restrict__ wt1, unsigned short* __restrict__ wt2,
                      unsigned short* __restrict__ relb, float* __restrict__ out,
                      int* __restrict__ deg, int* __restrict__ cursor) {
    int b = blockIdx.x, t = threadIdx.x;
    if (b < 50000) {                                   // x0 = relu(ent + bias)
        int i = b * 256 + t;
        float v = ent[i] + entb[i & (DIM - 1)];
        x1[i] = f2b(v > 0.0f ? v : 0.0f);
    } else if (b < 50320) {                            // wt[m][k]: bases|root
        int i = (b - 50000) * 256 + t;                 // 128*640
        int m = i / 640, k = i - m * 640;
        float v1, v2;
        if (k < 512) {
            int bb = k >> 7, kin = k & 127;
            v1 = bases1[(bb * 128 + kin) * 128 + m];
            v2 = bases2[(bb * 128 + kin) * 128 + m];
        } else {
            int kin = k - 512;
            v1 = root1[kin * 128 + m];
            v2 = root2[kin * 128 + m];
        }
        wt1[i] = f2b(v1);
        wt2[i] = f2b(v2);
    } else if (b < 50370) {                            // rel -> bf16
        int i = (b - 50320) * 256 + t;                 // 12800
        relb[i] = f2b(rel[i]);
    } else if (b < 51152) {                            // zero deg + cursor
        int j = (b - 50370) * 256 + t;                 // 200192 slots
        if (j < N_NODES) deg[j] = 0;
        else if (j < 2 * N_NODES) cursor[j - N_NODES] = 0;
    } else {                                           // penalty
        __shared__ float sm[256];
        float v = 0.0f;
        for (int i = t; i < RR * DIM; i += 256) { float x = rel[i]; v += x * x; }
        sm[t] = v;
        __syncthreads();
        for (int s = 128; s > 0; s >>= 1) {
            if (t < s) sm[t] += sm[t + s];
            __syncthreads();
        }
        if (t == 0) out[NE] = sm[0];
    }
}

// ---- fused aggregate + GEMM v5 -------------------------------------------
// r10 structure; WT staging software-pipelined through registers: chunk 0
// preloaded before phase A (latency hidden under gathers), chunk kc+1
// preloaded during chunk kc's MFMA. No exposed L2 latency in phase B.
#define ACC(A) { A[0] += (floatx2){w0, w0} * xv; \
                 A[1] += (floatx2){w1, w1} * xv; \
                 A[2] += (floatx2){w2, w2} * xv; \
                 A[3] += (floatx2){w3, w3} * xv; }

__global__ __launch_bounds__(512, 4) void k_fused(const unsigned short* __restrict__ X,
                                                  const int4* __restrict__ edesc,
                                                  const int* __restrict__ off,
                                                  const float* __restrict__ comp,
                                                  const unsigned short* __restrict__ WT,
                                                  const float* __restrict__ bias,
                                                  unsigned short* __restrict__ out,
                                                  int do_relu) {
    __shared__ __align__(16) unsigned short Sacc[4 * NPB * 128];   // 32 KB, 4 planes
    __shared__ __align__(16) unsigned short Bs[128 * 128];         // 32 KB, per-kc B chunk
    __shared__ float4 Cs[RR];                                      // 1.6 KB

    const int t = threadIdx.x, wid = t >> 6, lane = t & 63;
    const int rbase = blockIdx.x * NPB;
    const int quad = lane >> 4, lr = lane & 15;
    const int wr = wid & 1, wc = wid >> 1;             // 2 m-tiles x 4 n-slices

    // preload B chunk 0 + X fragments (kc=4) into registers: latency hidden
    // under phase A's gather traffic.
    uint4 breg[4];
    const int srow = t >> 4, sch = t & 15;             // staging coords (fixed per thread)
#pragma unroll
    for (int i = 0; i < 4; ++i)
        breg[i] = *(const uint4*)(WT + (size_t)(srow + i * 32) * 640 + sch * 8);
    bf16x8 ax[4];
    {
        int grow = rbase + wr * 16 + lr;               // always < N (3125*32 exact)
#pragma unroll
        for (int ks = 0; ks < 4; ++ks)
            ax[ks] = *(const bf16x8*)(X + (size_t)grow * 128 + ks * 32 + quad * 8);
    }

    if (t < RR) Cs[t] = ((const float4*)comp)[t];
    __syncthreads();

    // ---------------- phase A: wave owns rows [nbase, nbase+4) ----------------
    {
        const int nbase = rbase + wid * 4;
        const int lo = off[nbase], hi = off[nbase + 4];
        floatx2 a0[4], a1[4], a2[4], a3[4];
#pragma unroll
        for (int c = 0; c < 4; ++c) {
            a0[c] = (floatx2)0.0f; a1[c] = (floatx2)0.0f;
            a2[c] = (floatx2)0.0f; a3[c] = (floatx2)0.0f;
        }
        for (int base = lo; base < hi; base += 16) {
            int cnt = hi - base; if (cnt > 16) cnt = 16;
            int4 md = edesc[base + (lane & 15)];
            unsigned xp[16];
#pragma unroll
            for (int u = 0; u < 16; ++u) {             // 16 independent gathers
                int jc = (u < cnt) ? u : 0;
                int s = (int)__builtin_amdgcn_readlane((unsigned)md.x, (unsigned)jc);
                xp[u] = *(const unsigned*)(X + (size_t)s * 128 + 2 * lane);
            }
#pragma unroll
            for (int u = 0; u < 16; ++u) {
                if (u < cnt) {                         // wave-uniform guard
                    int row = (int)__builtin_amdgcn_readlane((unsigned)md.z, (unsigned)u) - nbase;
                    int tt  = (int)__builtin_amdgcn_readlane((unsigned)md.y, (unsigned)u) >> 19;
                    float w = __int_as_float(__builtin_amdgcn_readlane((unsigned)md.w, (unsigned)u));
                    float4 cc = Cs[tt];
                    floatx2 xv = {b2f(xp[u] & 0xffffu), b2f(xp[u] >> 16)};
                    float w0 = w * cc.x, w1 = w * cc.y, w2 = w * cc.z, w3 = w * cc.w;
                    if      (row == 0) ACC(a0)
                    else if (row == 1) ACC(a1)
                    else if (row == 2) ACC(a2)
                    else               ACC(a3)
                }
            }
        }
        // write 4 rows x 4 chunks, bf16-packed, xor-swizzled 16B chunks
        const int sw16 = lane >> 2, wo = 2 * (lane & 3);
#pragma unroll
        for (int r = 0; r < 4; ++r) {
            int R = wid * 4 + r;
            unsigned bo = (unsigned)(R * 128 + ((sw16 ^ (R & 15)) << 3) + wo);
            floatx2* A = (r == 0) ? a0 : (r == 1) ? a1 : (r == 2) ? a2 : a3;
#pragma unroll
            for (int c = 0; c < 4; ++c)
                *(unsigned*)(Sacc + c * (NPB * 128) + bo) = packbf(A[c].x, A[c].y);
        }
    }

    // ---------------- phase B: MFMA, m=32 n=128 K=640, pipelined Bs ----------------
    floatx4 acc[2];
    acc[0] = (floatx4)0.0f; acc[1] = (floatx4)0.0f;

#pragma unroll
    for (int kc = 0; kc < 5; ++kc) {
        __syncthreads();                               // Sacc ready (kc=0) / prev Bs consumed
#pragma unroll
        for (int i = 0; i < 4; ++i)                    // regs -> LDS (data already here)
            *(uint4*)(Bs + (srow + i * 32) * 128 + ((sch ^ ((srow + i * 32) & 15)) << 3)) = breg[i];
        if (kc < 4) {
#pragma unroll
            for (int i = 0; i < 4; ++i)                // preload next chunk; waits in next iter
                breg[i] = *(const uint4*)(WT + (size_t)(srow + i * 32) * 640 + (kc + 1) * 128 + sch * 8);
        }
        __syncthreads();                               // Bs ready
#pragma unroll
        for (int ks = 0; ks < 4; ++ks) {
            bf16x8 a, b0, b1;
            int R = wr * 16 + lr;
            if (kc < 4) {
                int ch = ((ks * 4 + quad) ^ (R & 15)) << 3;
                a = *(const bf16x8*)(Sacc + kc * (NPB * 128) + R * 128 + ch);
            } else {
                a = ax[ks];
            }
            int bch = ((ks * 4 + quad) ^ lr) << 3;
            b0 = *(const bf16x8*)(Bs + (wc * 32 + lr) * 128 + bch);
            b1 = *(const bf16x8*)(Bs + (wc * 32 + 16 + lr) * 128 + bch);
            acc[0] = __builtin_amdgcn_mfma_f32_16x16x32_bf16(a, b0, acc[0], 0, 0, 0);
            acc[1] = __builtin_amdgcn_mfma_f32_16x16x32_bf16(a, b1, acc[1], 0, 0, 0);
        }
    }

    // C/D layout: col=lane&15, row=quad*4+reg  [m89/m91-verified]
#pragma unroll
    for (int reg = 0; reg < 4; ++reg) {
        int R = wr * 16 + quad * 4 + reg;
        int grow = rbase + R;
#pragma unroll
        for (int nj = 0; nj < 2; ++nj) {
            int n = wc * 32 + nj * 16 + lr;
            float v = acc[nj][reg] + bias[n];
            if (do_relu) v = v > 0.0f ? v : 0.0f;
            out[(size_t)grow * 128 + n] = f2b(v);
        }
    }
}

// ---- DistMult score: flat, 16 lanes per edge (r8 measured-fastest) -------
__global__ __launch_bounds__(256) void k_score(const unsigned short* __restrict__ xf,
                                               const int* __restrict__ src, const int* __restrict__ dst,
                                               const int* __restrict__ et,
                                               const unsigned short* __restrict__ relb,
                                               float* __restrict__ out, int E) {
    int g = threadIdx.x >> 4, li = threadIdx.x & 15;
    int e = blockIdx.x * 16 + g;
    if (e >= E) return;
    int s = src[e], d = dst[e], tt = et[e];
    uint4 au = *(const uint4*)(xf + (size_t)s * 128 + li * 8);
    uint4 bu = *(const uint4*)(xf + (size_t)d * 128 + li * 8);
    uint4 ru = *(const uint4*)(relb + (size_t)tt * 128 + li * 8);
    float v;
    v  = b2f(au.x & 0xffffu) * b2f(ru.x & 0xffffu) * b2f(bu.x & 0xffffu);
    v += b2f(au.x >> 16)     * b2f(ru.x >> 16)     * b2f(bu.x >> 16);
    v += b2f(au.y & 0xffffu) * b2f(ru.y & 0xffffu) * b2f(bu.y & 0xffffu);
    v += b2f(au.y >> 16)     * b2f(ru.y >> 16)     * b2f(bu.y >> 16);
    v += b2f(au.z & 0xffffu) * b2f(ru.z & 0xffffu) * b2f(bu.z & 0xffffu);
    v += b2f(au.z >> 16)     * b2f(ru.z >> 16)     * b2f(bu.z >> 16);
    v += b2f(au.w & 0xffffu) * b2f(ru.w & 0xffffu) * b2f(bu.w & 0xffffu);
    v += b2f(au.w >> 16)     * b2f(ru.w >> 16)     * b2f(bu.w >> 16);
    v += __shfl_xor(v, 8, 16);
    v += __shfl_xor(v, 4, 16);
    v += __shfl_xor(v, 2, 16);
    v += __shfl_xor(v, 1, 16);
    if (li == 0) out[e] = v;
}

extern "C" void kernel_launch(void* const* d_in, const int* in_sizes, int n_in,
                              void* d_out, int out_size, void* d_ws, size_t ws_size,
                              hipStream_t stream) {
    (void)in_sizes; (void)n_in; (void)out_size; (void)ws_size;
    const int* edge_index = (const int*)d_in[0];
    const int* edge_type  = (const int*)d_in[1];
    const float* ent    = (const float*)d_in[2];
    const float* entb   = (const float*)d_in[3];
    const float* bases1 = (const float*)d_in[4];
    const float* comp1  = (const float*)d_in[5];
    const float* root1  = (const float*)d_in[6];
    const float* bias1  = (const float*)d_in[7];
    const float* bases2 = (const float*)d_in[8];
    const float* comp2  = (const float*)d_in[9];
    const float* root2  = (const float*)d_in[10];
    const float* bias2  = (const float*)d_in[11];
    const float* rel    = (const float*)d_in[12];
    const int* src = edge_index;
    const int* dst = edge_index + NE;

    char* ws = (char*)d_ws;
    size_t off_b = 0;
    auto alloc = [&](size_t bytes) { void* p = ws + off_b; off_b = (off_b + bytes + 255) & ~(size_t)255; return p; };

    unsigned short* x1   = (unsigned short*)alloc((size_t)N_NODES * 128 * 2);  // 25.6 MB
    unsigned short* x2   = (unsigned short*)alloc((size_t)N_NODES * 128 * 2);  // 25.6 MB
    unsigned short* wt1  = (unsigned short*)alloc(128 * 640 * 2);
    unsigned short* wt2  = (unsigned short*)alloc(128 * 640 * 2);
    unsigned short* relb = (unsigned short*)alloc(RR * DIM * 2);
    int*   deg    = (int*)alloc((size_t)N_NODES * 4);
    int*   cursor = (int*)alloc((size_t)N_NODES * 4);
    int*   offv   = (int*)alloc((size_t)(N_NODES + 1) * 4);
    int*   bsum   = (int*)alloc(NBLK * 4);
    int*   boff   = (int*)alloc(NBLK * 4);
    int4*  edesc  = (int4*)alloc((size_t)(NE + 64) * 16);                      // 6.4 MB + pad

    float* out = (float*)d_out;

    // k_pre first: x0/wt/rel/penalty + zero deg/cursor (replaces 2 memsets)
    k_pre<<<51153, 256, 0, stream>>>(ent, entb, bases1, root1, bases2, root2, rel,
                                     x1, wt1, wt2, relb, out, deg, cursor);
    k_deg<<<(NE + 255) / 256, 256, 0, stream>>>(dst, deg, NE);
    k_scan_block<<<NBLK, 256, 0, stream>>>(deg, bsum);
    k_scan_top<<<1, 256, 0, stream>>>(bsum, boff);
    k_scan_down<<<NBLK, 256, 0, stream>>>(deg, boff, offv);
    k_scatter<<<(NE + 255) / 256, 256, 0, stream>>>(src, dst, edge_type, offv, cursor, edesc, NE);
    k_norm2<<<(NE + 255) / 256, 256, 0, stream>>>(offv, edesc, NE);

    int fgrid = N_NODES / NPB;   // 3125 (exact)
    // layer 1: x1 -> x2 (relu)
    k_fused<<<fgrid, 512, 0, stream>>>(x1, edesc, offv, comp1, wt1, bias1, x2, 1);
    // layer 2: x2 -> x1 (no relu); x1 becomes xf
    k_fused<<<fgrid, 512, 0, stream>>>(x2, edesc, offv, comp2, wt2, bias2, x1, 0);
    // decode
    k_score<<<(NE + 15) / 16, 256, 0, stream>>>(x1, src, dst, edge_type, relb, out, NE);
}

// Round 12
// 392.985 us; speedup vs baseline: 1.5076x; 1.5076x over previous
//
#include <hip/hip_runtime.h>

#define N_NODES 100000
#define DIM     128
#define RR      100
#define NE      400000
#define NBLK    196    // ceil(N_NODES / 512)
#define NPB     32     // dst nodes per fused block (100000 = 3125 * 32, exact)

typedef float  floatx4 __attribute__((ext_vector_type(4)));
typedef float  floatx2 __attribute__((ext_vector_type(2)));
typedef __bf16 bf16x8  __attribute__((ext_vector_type(8)));

static __device__ __forceinline__ unsigned short f2b(float f) {
    union { float f; unsigned int i; } v; v.f = f;
    unsigned int u = v.i;
    unsigned int r = (u + 0x7fffu + ((u >> 16) & 1u)) >> 16;   // RNE
    return (unsigned short)r;
}
static __device__ __forceinline__ float b2f(unsigned int u16) {
    union { unsigned int i; float f; } v; v.i = u16 << 16; return v.f;
}
static __device__ __forceinline__ unsigned packbf(float a, float b) {
    return (unsigned)f2b(a) | ((unsigned)f2b(b) << 16);
}

// ---- per-dst degree ------------------------------------------------------
__global__ void k_deg(const int* __restrict__ dst, int* __restrict__ deg, int E) {
    int e = blockIdx.x * 256 + threadIdx.x;
    if (e < E) atomicAdd(&deg[dst[e]], 1);
}

// ---- 2-level exclusive scan over deg[N] ----------------------------------
__global__ void k_scan_block(const int* __restrict__ deg, int* __restrict__ bsum) {
    __shared__ int sm[256];
    int b = blockIdx.x, t = threadIdx.x;
    int i0 = b * 512 + 2 * t;
    int a = (i0     < N_NODES) ? deg[i0]     : 0;
    int c = (i0 + 1 < N_NODES) ? deg[i0 + 1] : 0;
    sm[t] = a + c;
    __syncthreads();
    for (int s = 128; s > 0; s >>= 1) { if (t < s) sm[t] += sm[t + s]; __syncthreads(); }
    if (t == 0) bsum[b] = sm[0];
}

__global__ void k_scan_top(const int* __restrict__ bsum, int* __restrict__ boff) {
    __shared__ int sm[256];
    int t = threadIdx.x;
    int v = (t < NBLK) ? bsum[t] : 0;
    sm[t] = v;
    __syncthreads();
    for (int s = 1; s < 256; s <<= 1) {
        int u = (t >= s) ? sm[t - s] : 0;
        __syncthreads();
        sm[t] += u;
        __syncthreads();
    }
    if (t < NBLK) boff[t] = sm[t] - v;   // exclusive
}

__global__ void k_scan_down(const int* __restrict__ deg, const int* __restrict__ boff,
                            int* __restrict__ off) {
    __shared__ int sm[256];
    int b = blockIdx.x, t = threadIdx.x;
    int i0 = b * 512 + 2 * t;
    int a = (i0     < N_NODES) ? deg[i0]     : 0;
    int c = (i0 + 1 < N_NODES) ? deg[i0 + 1] : 0;
    int ts = a + c;
    sm[t] = ts;
    __syncthreads();
    for (int s = 1; s < 256; s <<= 1) {
        int u = (t >= s) ? sm[t - s] : 0;
        __syncthreads();
        sm[t] += u;
        __syncthreads();
    }
    int base = boff[b] + (sm[t] - ts);
    if (i0     < N_NODES) off[i0]     = base;
    if (i0 + 1 < N_NODES) off[i0 + 1] = base + a;
    if (b == 0 && t == 0) off[N_NODES] = NE;
}

// ---- scatter edges into dst-sorted CSR: desc = {src, et<<19|eidx, dst, norm}
__global__ void k_scatter(const int* __restrict__ src, const int* __restrict__ dst,
                          const int* __restrict__ et, const int* __restrict__ off,
                          int* __restrict__ cursor, int4* __restrict__ edesc, int E) {
    int e = blockIdx.x * 256 + threadIdx.x;
    if (e >= E) return;
    int d = dst[e];
    int pos = off[d] + atomicAdd(&cursor[d], 1);
    edesc[pos] = make_int4(src[e], (et[e] << 19) | e, d, 0);
}

// ---- schlichtkrull norm: one thread per CSR slot, O(deg) scan ------------
__global__ void k_norm2(const int* __restrict__ off, int4* __restrict__ edesc, int E) {
    int p = blockIdx.x * 256 + threadIdx.x;
    if (p >= E) return;
    int4 me = edesc[p];
    int myt = me.y >> 19;
    int p0 = off[me.z], p1 = off[me.z + 1];
    int c = 0;
    for (int j = p0; j < p1; ++j)
        c += ((((const int*)edesc)[4 * j + 1] >> 19) == myt) ? 1 : 0;
    ((int*)edesc)[4 * p + 3] = __float_as_int(1.0f / (float)c);
}

// ---- fused preprocessing: x0 | wt transpose | rel bf16 | penalty | zero --
__global__ void k_pre(const float* __restrict__ ent, const float* __restrict__ entb,
                      const float* __restrict__ bases1, const float* __restrict__ root1,
                      const float* __restrict__ bases2, const float* __restrict__ root2,
                      const float* __restrict__ rel,
                      unsigned short* __restrict__ x1,
                      unsigned short* __restrict__ wt1, unsigned short* __restrict__ wt2,
                      unsigned short* __restrict__ relb, float* __restrict__ out,
                      int* __restrict__ deg, int* __restrict__ cursor) {
    int b = blockIdx.x, t = threadIdx.x;
    if (b < 50000) {                                   // x0 = relu(ent + bias)
        int i = b * 256 + t;
        float v = ent[i] + entb[i & (DIM - 1)];
        x1[i] = f2b(v > 0.0f ? v : 0.0f);
    } else if (b < 50320) {                            // wt[m][k]: bases|root
        int i = (b - 50000) * 256 + t;                 // 128*640
        int m = i / 640, k = i - m * 640;
        float v1, v2;
        if (k < 512) {
            int bb = k >> 7, kin = k & 127;
            v1 = bases1[(bb * 128 + kin) * 128 + m];
            v2 = bases2[(bb * 128 + kin) * 128 + m];
        } else {
            int kin = k - 512;
            v1 = root1[kin * 128 + m];
            v2 = root2[kin * 128 + m];
        }
        wt1[i] = f2b(v1);
        wt2[i] = f2b(v2);
    } else if (b < 50370) {                            // rel -> bf16
        int i = (b - 50320) * 256 + t;                 // 12800
        relb[i] = f2b(rel[i]);
    } else if (b < 51152) {                            // zero deg + cursor
        int j = (b - 50370) * 256 + t;                 // 200192 slots
        if (j < N_NODES) deg[j] = 0;
        else if (j < 2 * N_NODES) cursor[j - N_NODES] = 0;
    } else {                                           // penalty
        __shared__ float sm[256];
        float v = 0.0f;
        for (int i = t; i < RR * DIM; i += 256) { float x = rel[i]; v += x * x; }
        sm[t] = v;
        __syncthreads();
        for (int s = 128; s > 0; s >>= 1) {
            if (t < s) sm[t] += sm[t + s];
            __syncthreads();
        }
        if (t == 0) out[NE] = sm[0];
    }
}

// ---- fused aggregate + GEMM (r10-measured-best form) ---------------------
// Block = 512 thr (8 waves), 32 dst nodes; wave owns 4 consecutive nodes.
// Phase A: 16-edge batches, 16 prefetched gathers (readlane bases), pk_fma
// fp32 register acc, single bf16 LDS write per (row,chunk). Phase B: MFMA
// K=640, B chunk staged cooperatively into LDS per kc; X fragments (kc=4)
// prefetched AFTER phase A (short live range — r11's cross-phase preload
// spilled to scratch: WRITE_SIZE 25->214 MB, 97->202 us. Do not hoist.)
#define ACC(A) { A[0] += (floatx2){w0, w0} * xv; \
                 A[1] += (floatx2){w1, w1} * xv; \
                 A[2] += (floatx2){w2, w2} * xv; \
                 A[3] += (floatx2){w3, w3} * xv; }

__global__ __launch_bounds__(512, 4) void k_fused(const unsigned short* __restrict__ X,
                                                  const int4* __restrict__ edesc,
                                                  const int* __restrict__ off,
                                                  const float* __restrict__ comp,
                                                  const unsigned short* __restrict__ WT,
                                                  const float* __restrict__ bias,
                                                  unsigned short* __restrict__ out,
                                                  int do_relu) {
    __shared__ __align__(16) unsigned short Sacc[4 * NPB * 128];   // 32 KB, 4 planes
    __shared__ __align__(16) unsigned short Bs[128 * 128];         // 32 KB, per-kc B chunk
    __shared__ float4 Cs[RR];                                      // 1.6 KB

    const int t = threadIdx.x, wid = t >> 6, lane = t & 63;
    const int rbase = blockIdx.x * NPB;

    if (t < RR) Cs[t] = ((const float4*)comp)[t];
    __syncthreads();

    // ---------------- phase A: wave owns rows [nbase, nbase+4) ----------------
    {
        const int nbase = rbase + wid * 4;
        const int lo = off[nbase], hi = off[nbase + 4];
        floatx2 a0[4], a1[4], a2[4], a3[4];
#pragma unroll
        for (int c = 0; c < 4; ++c) {
            a0[c] = (floatx2)0.0f; a1[c] = (floatx2)0.0f;
            a2[c] = (floatx2)0.0f; a3[c] = (floatx2)0.0f;
        }
        for (int base = lo; base < hi; base += 16) {
            int cnt = hi - base; if (cnt > 16) cnt = 16;
            int4 md = edesc[base + (lane & 15)];
            unsigned xp[16];
#pragma unroll
            for (int u = 0; u < 16; ++u) {             // 16 independent gathers
                int jc = (u < cnt) ? u : 0;
                int s = (int)__builtin_amdgcn_readlane((unsigned)md.x, (unsigned)jc);
                xp[u] = *(const unsigned*)(X + (size_t)s * 128 + 2 * lane);
            }
#pragma unroll
            for (int u = 0; u < 16; ++u) {
                if (u < cnt) {                         // wave-uniform guard
                    int row = (int)__builtin_amdgcn_readlane((unsigned)md.z, (unsigned)u) - nbase;
                    int tt  = (int)__builtin_amdgcn_readlane((unsigned)md.y, (unsigned)u) >> 19;
                    float w = __int_as_float(__builtin_amdgcn_readlane((unsigned)md.w, (unsigned)u));
                    float4 cc = Cs[tt];
                    floatx2 xv = {b2f(xp[u] & 0xffffu), b2f(xp[u] >> 16)};
                    float w0 = w * cc.x, w1 = w * cc.y, w2 = w * cc.z, w3 = w * cc.w;
                    if      (row == 0) ACC(a0)
                    else if (row == 1) ACC(a1)
                    else if (row == 2) ACC(a2)
                    else               ACC(a3)
                }
            }
        }
        // write 4 rows x 4 chunks, bf16-packed, xor-swizzled 16B chunks
        const int sw16 = lane >> 2, wo = 2 * (lane & 3);
#pragma unroll
        for (int r = 0; r < 4; ++r) {
            int R = wid * 4 + r;
            unsigned bo = (unsigned)(R * 128 + ((sw16 ^ (R & 15)) << 3) + wo);
            floatx2* A = (r == 0) ? a0 : (r == 1) ? a1 : (r == 2) ? a2 : a3;
#pragma unroll
            for (int c = 0; c < 4; ++c)
                *(unsigned*)(Sacc + c * (NPB * 128) + bo) = packbf(A[c].x, A[c].y);
        }
    }

    // ---------------- phase B: MFMA, m=32 n=128 K=640, Bs in LDS ----------------
    const int quad = lane >> 4, lr = lane & 15;
    const int wr = wid & 1, wc = wid >> 1;             // 2 m-tiles x 4 n-slices

    // prefetch X fragments for kc=4 (hidden behind kc=0..3 compute)
    bf16x8 ax[4];
    {
        int grow = rbase + wr * 16 + lr;               // always < N (3125*32 exact)
#pragma unroll
        for (int ks = 0; ks < 4; ++ks)
            ax[ks] = *(const bf16x8*)(X + (size_t)grow * 128 + ks * 32 + quad * 8);
    }

    floatx4 acc[2];
    acc[0] = (floatx4)0.0f; acc[1] = (floatx4)0.0f;

#pragma unroll
    for (int kc = 0; kc < 5; ++kc) {
        __syncthreads();                               // Sacc ready / prev Bs consumed
#pragma unroll
        for (int i = 0; i < 4; ++i) {                  // stage B chunk: 128 rows x 16 chunks
            int idx = i * 512 + t;
            int row = idx >> 4, ch = idx & 15;
            uint4 w = *(const uint4*)(WT + (size_t)row * 640 + kc * 128 + ch * 8);
            *(uint4*)(Bs + row * 128 + ((ch ^ (row & 15)) << 3)) = w;
        }
        __syncthreads();
#pragma unroll
        for (int ks = 0; ks < 4; ++ks) {
            bf16x8 a, b0, b1;
            int R = wr * 16 + lr;
            if (kc < 4) {
                int ch = ((ks * 4 + quad) ^ (R & 15)) << 3;
                a = *(const bf16x8*)(Sacc + kc * (NPB * 128) + R * 128 + ch);
            } else {
                a = ax[ks];
            }
            int sch = ((ks * 4 + quad) ^ lr) << 3;
            b0 = *(const bf16x8*)(Bs + (wc * 32 + lr) * 128 + sch);
            b1 = *(const bf16x8*)(Bs + (wc * 32 + 16 + lr) * 128 + sch);
            acc[0] = __builtin_amdgcn_mfma_f32_16x16x32_bf16(a, b0, acc[0], 0, 0, 0);
            acc[1] = __builtin_amdgcn_mfma_f32_16x16x32_bf16(a, b1, acc[1], 0, 0, 0);
        }
    }

    // C/D layout: col=lane&15, row=quad*4+reg  [m89/m91-verified]
#pragma unroll
    for (int reg = 0; reg < 4; ++reg) {
        int R = wr * 16 + quad * 4 + reg;
        int grow = rbase + R;
#pragma unroll
        for (int nj = 0; nj < 2; ++nj) {
            int n = wc * 32 + nj * 16 + lr;
            float v = acc[nj][reg] + bias[n];
            if (do_relu) v = v > 0.0f ? v : 0.0f;
            out[(size_t)grow * 128 + n] = f2b(v);
        }
    }
}

// ---- DistMult score: flat, 16 lanes per edge (r8 measured-fastest) -------
__global__ __launch_bounds__(256) void k_score(const unsigned short* __restrict__ xf,
                                               const int* __restrict__ src, const int* __restrict__ dst,
                                               const int* __restrict__ et,
                                               const unsigned short* __restrict__ relb,
                                               float* __restrict__ out, int E) {
    int g = threadIdx.x >> 4, li = threadIdx.x & 15;
    int e = blockIdx.x * 16 + g;
    if (e >= E) return;
    int s = src[e], d = dst[e], tt = et[e];
    uint4 au = *(const uint4*)(xf + (size_t)s * 128 + li * 8);
    uint4 bu = *(const uint4*)(xf + (size_t)d * 128 + li * 8);
    uint4 ru = *(const uint4*)(relb + (size_t)tt * 128 + li * 8);
    float v;
    v  = b2f(au.x & 0xffffu) * b2f(ru.x & 0xffffu) * b2f(bu.x & 0xffffu);
    v += b2f(au.x >> 16)     * b2f(ru.x >> 16)     * b2f(bu.x >> 16);
    v += b2f(au.y & 0xffffu) * b2f(ru.y & 0xffffu) * b2f(bu.y & 0xffffu);
    v += b2f(au.y >> 16)     * b2f(ru.y >> 16)     * b2f(bu.y >> 16);
    v += b2f(au.z & 0xffffu) * b2f(ru.z & 0xffffu) * b2f(bu.z & 0xffffu);
    v += b2f(au.z >> 16)     * b2f(ru.z >> 16)     * b2f(bu.z >> 16);
    v += b2f(au.w & 0xffffu) * b2f(ru.w & 0xffffu) * b2f(bu.w & 0xffffu);
    v += b2f(au.w >> 16)     * b2f(ru.w >> 16)     * b2f(bu.w >> 16);
    v += __shfl_xor(v, 8, 16);
    v += __shfl_xor(v, 4, 16);
    v += __shfl_xor(v, 2, 16);
    v += __shfl_xor(v, 1, 16);
    if (li == 0) out[e] = v;
}

extern "C" void kernel_launch(void* const* d_in, const int* in_sizes, int n_in,
                              void* d_out, int out_size, void* d_ws, size_t ws_size,
                              hipStream_t stream) {
    (void)in_sizes; (void)n_in; (void)out_size; (void)ws_size;
    const int* edge_index = (const int*)d_in[0];
    const int* edge_type  = (const int*)d_in[1];
    const float* ent    = (const float*)d_in[2];
    const float* entb   = (const float*)d_in[3];
    const float* bases1 = (const float*)d_in[4];
    const float* comp1  = (const float*)d_in[5];
    const float* root1  = (const float*)d_in[6];
    const float* bias1  = (const float*)d_in[7];
    const float* bases2 = (const float*)d_in[8];
    const float* comp2  = (const float*)d_in[9];
    const float* root2  = (const float*)d_in[10];
    const float* bias2  = (const float*)d_in[11];
    const float* rel    = (const float*)d_in[12];
    const int* src = edge_index;
    const int* dst = edge_index + NE;

    char* ws = (char*)d_ws;
    size_t off_b = 0;
    auto alloc = [&](size_t bytes) { void* p = ws + off_b; off_b = (off_b + bytes + 255) & ~(size_t)255; return p; };

    unsigned short* x1   = (unsigned short*)alloc((size_t)N_NODES * 128 * 2);  // 25.6 MB
    unsigned short* x2   = (unsigned short*)alloc((size_t)N_NODES * 128 * 2);  // 25.6 MB
    unsigned short* wt1  = (unsigned short*)alloc(128 * 640 * 2);
    unsigned short* wt2  = (unsigned short*)alloc(128 * 640 * 2);
    unsigned short* relb = (unsigned short*)alloc(RR * DIM * 2);
    int*   deg    = (int*)alloc((size_t)N_NODES * 4);
    int*   cursor = (int*)alloc((size_t)N_NODES * 4);
    int*   offv   = (int*)alloc((size_t)(N_NODES + 1) * 4);
    int*   bsum   = (int*)alloc(NBLK * 4);
    int*   boff   = (int*)alloc(NBLK * 4);
    int4*  edesc  = (int4*)alloc((size_t)(NE + 64) * 16);                      // 6.4 MB + pad

    float* out = (float*)d_out;

    // k_pre first: x0/wt/rel/penalty + zero deg/cursor (replaces 2 memsets)
    k_pre<<<51153, 256, 0, stream>>>(ent, entb, bases1, root1, bases2, root2, rel,
                                     x1, wt1, wt2, relb, out, deg, cursor);
    k_deg<<<(NE + 255) / 256, 256, 0, stream>>>(dst, deg, NE);
    k_scan_block<<<NBLK, 256, 0, stream>>>(deg, bsum);
    k_scan_top<<<1, 256, 0, stream>>>(bsum, boff);
    k_scan_down<<<NBLK, 256, 0, stream>>>(deg, boff, offv);
    k_scatter<<<(NE + 255) / 256, 256, 0, stream>>>(src, dst, edge_type, offv, cursor, edesc, NE);
    k_norm2<<<(NE + 255) / 256, 256, 0, stream>>>(offv, edesc, NE);

    int fgrid = N_NODES / NPB;   // 3125 (exact)
    // layer 1: x1 -> x2 (relu)
    k_fused<<<fgrid, 512, 0, stream>>>(x1, edesc, offv, comp1, wt1, bias1, x2, 1);
    // layer 2: x2 -> x1 (no relu); x1 becomes xf
    k_fused<<<fgrid, 512, 0, stream>>>(x2, edesc, offv, comp2, wt2, bias2, x1, 0);
    // decode
    k_score<<<(NE + 15) / 16, 256, 0, stream>>>(x1, src, dst, edge_type, relb, out, NE);
}